// Round 5
// baseline (245.522 us; speedup 1.0000x reference)
//
#include <hip/hip_runtime.h>
#include <hip/hip_bf16.h>
#include <cmath>

#define DIM 512
#define HID 256
#define ROWS_PB 32       // rows per block
#define NCHUNK 16        // K chunks of 32
#define CB 16384         // chunk bytes: 32k * 256c * 2B

typedef __attribute__((ext_vector_type(8))) short short8;
typedef __attribute__((ext_vector_type(4))) float f32x4;

__device__ __forceinline__ unsigned short f2bf(float f) {
  union { float f; unsigned u; } v; v.f = f;
  unsigned u = v.u;
  return (unsigned short)((u + 0x7FFFu + ((u >> 16) & 1u)) >> 16);
}

// Pre-swizzle W1 (fp32 [512,256] row-major) into bf16 MFMA fragment order:
// w1s[((k>>3)*HID + c)*8 + (k&7)]. K-chunk c (32 k's) is the contiguous
// 16 KB at byte offset c*16384 — a linear global_load_lds copy.
__global__ void w1_swz_kernel(const float* __restrict__ W1,
                              unsigned short* __restrict__ w1s) {
  int tid = blockIdx.x * blockDim.x + threadIdx.x;
  if (tid >= DIM * HID) return;
  int k = tid / HID;
  int c = tid - k * HID;
  w1s[(((k >> 3) * HID) + c) * 8 + (k & 7)] = f2bf(W1[tid]);
}

__device__ __forceinline__ short8 cvt8(const f32x4 p0, const f32x4 p1) {
  short8 r;
  r[0] = (short)f2bf(p0[0]); r[1] = (short)f2bf(p0[1]);
  r[2] = (short)f2bf(p0[2]); r[3] = (short)f2bf(p0[3]);
  r[4] = (short)f2bf(p1[0]); r[5] = (short)f2bf(p1[1]);
  r[6] = (short)f2bf(p1[2]); r[7] = (short)f2bf(p1[3]);
  return r;
}

// 4 waves per block, 32 rows: wave w -> src = w&1 (z1/z2), row-tile = w>>1.
// T3/T4 schedule: raw s_barrier + counted vmcnt(2) (never 0 in-loop) keeps
// the next B-stage and a 2-deep A-prefetch in flight across barriers.
// Per-iter VMEM FIFO (issue order pinned by sched_barrier(0)):
//   queue at wait: [A[c](2), B[c](4), A[c+1](2)] -> vmcnt(2) leaves A[c+1].
__global__ __launch_bounds__(256, 4) void fa_main_kernel(
    const float* __restrict__ z1, const float* __restrict__ z2,
    const unsigned short* __restrict__ w1s,
    const float* __restrict__ b1, const float* __restrict__ W2,
    const float* __restrict__ b2, float* __restrict__ out, int n) {
  __shared__ unsigned short Bs[2][CB / 2];
  __shared__ float xs[2][ROWS_PB];

  const int t = threadIdx.x;
  const int w = t >> 6;
  const int l = t & 63;
  const int l15 = l & 15, l16 = l >> 4;
  const int src = w & 1;
  const int tile = w >> 1;
  const int row0 = blockIdx.x * ROWS_PB;
  const int myrow = row0 + tile * 16 + l15;
  const bool rok = myrow < n;
  const float* zz = src ? z2 : z1;
  const float* ap = zz + (size_t)myrow * DIM + (l16 << 3);
  const f32x4 zf4 = (f32x4){0.f, 0.f, 0.f, 0.f};

  // Stage chunk cc's 16 KB: 4 gload_lds/wave, LDS dest wave-uniform + lane*16.
  auto STAGE = [&](int cc) {
    const char* gsrc = (const char*)w1s + cc * CB + l * 16;
    char* ldst = (char*)&Bs[cc & 1][0];
#pragma unroll
    for (int r = 0; r < 4; ++r) {
      const int rr = w + r * 4;
      __builtin_amdgcn_global_load_lds(
          (const __attribute__((address_space(1))) void*)(gsrc + rr * 1024),
          (__attribute__((address_space(3))) void*)(ldst + rr * 1024), 16, 0,
          0);
    }
  };

  f32x4 pa[2][2];
  // Prologue: B[0] stage, then A[0] -> slot0, A[1] -> slot1 (order pinned).
  STAGE(0);
  __builtin_amdgcn_sched_barrier(0);
  pa[0][0] = rok ? *(const f32x4*)(ap) : zf4;
  pa[0][1] = rok ? *(const f32x4*)(ap + 4) : zf4;
  pa[1][0] = rok ? *(const f32x4*)(ap + 32) : zf4;
  pa[1][1] = rok ? *(const f32x4*)(ap + 36) : zf4;
  __builtin_amdgcn_sched_barrier(0);

  f32x4 acc[16];
#pragma unroll
  for (int f = 0; f < 16; ++f) acc[f] = zf4;

#pragma unroll
  for (int c = 0; c < NCHUNK; ++c) {
    // Wait: my B[c] + A[c] landed; keep A[c+1] in flight (tail: drain all).
    if (c < NCHUNK - 1)
      asm volatile("s_waitcnt vmcnt(2)" ::: "memory");
    else
      asm volatile("s_waitcnt vmcnt(0)" ::: "memory");
    __builtin_amdgcn_s_barrier();  // all waves' B[c] landed; buf c^1 free
    __builtin_amdgcn_sched_barrier(0);
    if (c + 1 < NCHUNK) STAGE(c + 1);
    __builtin_amdgcn_sched_barrier(0);
    const short8 af = cvt8(pa[c & 1][0], pa[c & 1][1]);
    if (c + 2 < NCHUNK) {
      const float* apn = ap + ((c + 2) << 5);
      pa[c & 1][0] = rok ? *(const f32x4*)(apn) : zf4;
      pa[c & 1][1] = rok ? *(const f32x4*)(apn + 4) : zf4;
    }
    __builtin_amdgcn_sched_barrier(0);
    const short8* bp = (const short8*)&Bs[c & 1][0] + (l16 << 8) + l15;
#pragma unroll
    for (int f = 0; f < 16; ++f) {
      const short8 bf = bp[f << 4];
      acc[f] = __builtin_amdgcn_mfma_f32_16x16x32_bf16(af, bf, acc[f], 0, 0, 0);
    }
  }

  // Per-row logit: x = sum_c relu(H+b1)*W2 (+b2 cancels in the pair diff).
  // C/D layout: hidden col = l15 + 16f, row-in-tile = l16*4 + r.
  float part[4] = {0.f, 0.f, 0.f, 0.f};
#pragma unroll
  for (int f = 0; f < 16; ++f) {
    const int cc = (f << 4) + l15;
    const float w2v = W2[cc];
    const float b1v = b1[cc];
#pragma unroll
    for (int r = 0; r < 4; ++r) {
      const float h = acc[f][r] + b1v;
      part[r] += (h > 0.f) ? h * w2v : 0.f;
    }
  }
#pragma unroll
  for (int r = 0; r < 4; ++r) {
#pragma unroll
    for (int m = 1; m < 16; m <<= 1) part[r] += __shfl_xor(part[r], m, 16);
  }
  if (l15 == 0) {
#pragma unroll
    for (int r = 0; r < 4; ++r)
      xs[src][tile * 16 + (l16 << 2) + r] = part[r];
  }
  __syncthreads();

  // Epilogue: wave w covers rows tile*16..+16, column half (w&1)*256..+256.
  const int colh = src << 8;
#pragma unroll 1
  for (int r = 0; r < 16; ++r) {
    const int rl = tile * 16 + r;
    const int grow = row0 + rl;
    if (grow < n) {
      const float d = xs[1][rl] - xs[0][rl];  // y - x
      const float sx = 1.f / (1.f + __expf(d));
      const float sy = 1.f - sx;
      const size_t off = (size_t)grow * DIM + colh + (l << 2);
      const f32x4 a4 = *(const f32x4*)(z1 + off);
      const f32x4 b4 = *(const f32x4*)(z2 + off);
      f32x4 o;
      o[0] = sx * a4[0] + sy * b4[0];
      o[1] = sx * a4[1] + sy * b4[1];
      o[2] = sx * a4[2] + sy * b4[2];
      o[3] = sx * a4[3] + sy * b4[3];
      *(f32x4*)(out + off) = o;
    }
  }
}

extern "C" void kernel_launch(void* const* d_in, const int* in_sizes, int n_in,
                              void* d_out, int out_size, void* d_ws,
                              size_t ws_size, hipStream_t stream) {
  const float* z1 = (const float*)d_in[0];
  const float* z2 = (const float*)d_in[1];
  const float* W1 = (const float*)d_in[2];
  const float* b1 = (const float*)d_in[3];
  const float* W2 = (const float*)d_in[4];
  const float* b2 = (const float*)d_in[5];
  float* out = (float*)d_out;
  const int n = in_sizes[0] / DIM;
  unsigned short* w1s = (unsigned short*)d_ws;  // 512*256*2 = 256 KB

  hipLaunchKernelGGL(w1_swz_kernel, dim3((DIM * HID + 255) / 256), dim3(256),
                     0, stream, W1, w1s);
  const int nwg = (n + ROWS_PB - 1) / ROWS_PB;
  hipLaunchKernelGGL(fa_main_kernel, dim3(nwg), dim3(256), 0, stream, z1, z2,
                     w1s, b1, W2, b2, out, n);
}